// Round 1
// 127.067 us; speedup vs baseline: 1.0538x; 1.0538x over previous
//
#include <hip/hip_runtime.h>
#include <hip/hip_bf16.h>

// Problem constants
#define NB    8
#define CCH   64      // CIN = COUT = 64
#define HH    128
#define WW    128
#define KTAP  9
#define HW    (HH * WW)            // 16384
#define KSTEPS 18                  // 576 / 32
#define NW    36864                // weight elements

typedef _Float16 f16x8 __attribute__((ext_vector_type(8)));
typedef _Float16 f16x2 __attribute__((ext_vector_type(2)));
typedef __attribute__((ext_vector_type(4))) float f32x4;

// RNE f32 pair -> packed f16x2 (as uint)
__device__ inline unsigned int pack_f16(float a, float b) {
    f16x2 h;
    h[0] = (_Float16)a;   // v_cvt_f16_f32 (RNE)
    h[1] = (_Float16)b;
    return __builtin_bit_cast(unsigned int, h);
}

__device__ inline f16x8 as_f16x8(uint4 u) { return __builtin_bit_cast(f16x8, u); }

// ---------- K1: transpose x NCHW f32 -> xt NHWC f16 (blocks 0..2047)
//             + weight quant into MFMA B frags (blocks 2048..2065, redundant maxabs)
__global__ __launch_bounds__(256) void prep_kernel(const float* __restrict__ x,
                                                   const float* __restrict__ w,
                                                   unsigned int* __restrict__ xt32,
                                                   uint4* __restrict__ bq) {
    __shared__ float tile[64 * 65];
    const int t = threadIdx.x;
    const int bid = blockIdx.x;

    if (bid < 2048) {
        // ---- transpose 64 channels x 64 pixels ----
        const int n = bid >> 8;
        const int pbase = (bid & 255) * 64;
        #pragma unroll
        for (int i = 0; i < 4; i++) {
            int idx = i * 256 + t;
            int c = idx >> 4, f4 = idx & 15;
            float4 v = *(const float4*)&x[((size_t)(n * CCH + c)) * HW + pbase + f4 * 4];
            float* d = &tile[c * 65 + f4 * 4];
            d[0] = v.x; d[1] = v.y; d[2] = v.z; d[3] = v.w;
        }
        __syncthreads();
        const int px = t >> 2, c4 = t & 3;
        float f[16];
        #pragma unroll
        for (int j = 0; j < 16; j++) f[j] = tile[(c4 * 16 + j) * 65 + px];
        unsigned int o8[8];
        #pragma unroll
        for (int i = 0; i < 8; i++) o8[i] = pack_f16(f[2 * i], f[2 * i + 1]);
        uint4* dst = (uint4*)&xt32[((size_t)(n * HW + pbase + px)) * 32 + c4 * 8];
        dst[0] = make_uint4(o8[0], o8[1], o8[2], o8[3]);
        dst[1] = make_uint4(o8[4], o8[5], o8[6], o8[7]);
    } else {
        // ---- each of 18 blocks: full maxabs (parallel, redundant) + 256 recs ----
        float m0 = 0.f, m1 = 0.f, m2 = 0.f, m3 = 0.f;
        for (int i = t; i < NW; i += 1024) {       // 36 iters, 4-way ILP
            m0 = fmaxf(m0, fabsf(w[i]));
            m1 = fmaxf(m1, fabsf(w[i + 256]));
            m2 = fmaxf(m2, fabsf(w[i + 512]));
            m3 = fmaxf(m3, fabsf(w[i + 768]));
        }
        float m = fmaxf(fmaxf(m0, m1), fmaxf(m2, m3));
        #pragma unroll
        for (int off = 32; off > 0; off >>= 1)
            m = fmaxf(m, __shfl_down(m, off));
        if ((t & 63) == 0) tile[t >> 6] = m;
        __syncthreads();
        m = fmaxf(fmaxf(tile[0], tile[1]), fmaxf(tile[2], tile[3]));
        const float scale = fmaxf(m, 1e-8f) / 127.f;
        const float inv_scale = 1.f / scale;

        const int rec = (bid - 2048) * 256 + t;    // 0..4607
        int nt  = rec / (KSTEPS * 64);
        int rem = rec - nt * (KSTEPS * 64);
        int s    = rem >> 6;
        int lane = rem & 63;
        int quad = lane >> 4, n16 = lane & 15;
        int o = nt * 16 + n16;
        unsigned int u[4];
        #pragma unroll
        for (int jj = 0; jj < 4; jj++) {
            float q[2];
            #pragma unroll
            for (int h = 0; h < 2; h++) {
                int k   = s * 32 + quad * 8 + 2 * jj + h;
                int c   = k & 63;
                int tap = k >> 6;
                float v  = w[(o * CCH + c) * KTAP + tap];
                float qq = rintf(v * inv_scale);          // RNE = jnp.round
                q[h] = fminf(fmaxf(qq, -128.f), 127.f) * scale;
            }
            u[jj] = pack_f16(q[0], q[1]);
        }
        bq[rec] = make_uint4(u[0], u[1], u[2], u[3]);
    }
}

// ---------- K2: deformable-sample + MFMA GEMM, 1 tap per barrier stage ----------
// Block = 64 px x 64 outs; wave w = 16-out slab (o = w*16+n16), all 64 px (4 m-tiles).
// 9 stages of {blend tap -> LDS, prefetch next tap, barrier, 8 MFMA}.
// Gather coalescing: 8 lanes cover one 128B corner row (8 lines/inst, was 16).
// LDS: Abuf 16KB (was 32KB) -> 6-7 blocks/CU resident (was 4).
__global__ __launch_bounds__(256) void deform_mfma(const unsigned short* __restrict__ xt,
                                                   const float* __restrict__ offset,
                                                   const uint4* __restrict__ bq,
                                                   float* __restrict__ out) {
    __shared__ __align__(16) _Float16 Abuf[2][4096];  // 16384 B: [stage-buf][64px*64ch]
    __shared__ unsigned int SC[576];       // packed clamped corners per (tap,px)
    __shared__ uint2 SW[576];              // packed f16 bilinear weights

    const int t    = threadIdx.x;
    const int wid  = t >> 6;
    const int lane = t & 63;
    const int quad = lane >> 4, n16 = lane & 15;
    const int bid  = blockIdx.x;
    const int n    = bid & 7;                 // image -> XCD swizzle
    const int px0  = (bid >> 3) * 64;
    const int pg   = t >> 3;                  // pixel-group 0..31 (round adds 32)
    const int q8   = t & 7;                   // 16B chunk within 128B pixel row

    const char* xb = (const char*)(xt + (size_t)n * HW * CCH);
    const float* offn = offset + (size_t)n * 2 * KTAP * HW;

    // ---- setup: one task per (tap, pixel), cooperative across 256 threads ----
    for (int u = t; u < 576; u += 256) {
        const int tap = u >> 6, p = u & 63;
        const int ppx = px0 + p;
        const int ho = ppx >> 7, wo = ppx & 127;
        const int ky = tap / 3, kx = tap - 3 * ky;
        const float py  = (float)(ho - 1 + ky) + offn[(2 * tap) * HW + ppx];
        const float pxf = (float)(wo - 1 + kx) + offn[(2 * tap + 1) * HW + ppx];
        const float fy = floorf(py), fx = floorf(pxf);
        const int y0 = (int)fy, x0 = (int)fx;
        const float dy = py - fy, dx = pxf - fx;
        const int y1 = y0 + 1, x1 = x0 + 1;
        const bool vy0 = (y0 >= 0) && (y0 < HH);
        const bool vy1 = (y1 >= 0) && (y1 < HH);
        const bool vx0 = (x0 >= 0) && (x0 < WW);
        const bool vx1 = (x1 >= 0) && (x1 < WW);
        const int y0c = min(max(y0, 0), HH - 1);
        const int y1c = min(max(y1, 0), HH - 1);
        const int x0c = min(max(x0, 0), WW - 1);
        const int x1c = min(max(x1, 0), WW - 1);
        const float w00 = (1.f - dy) * (1.f - dx) * ((vy0 && vx0) ? 1.f : 0.f);
        const float w01 = (1.f - dy) * dx         * ((vy0 && vx1) ? 1.f : 0.f);
        const float w10 = dy * (1.f - dx)         * ((vy1 && vx0) ? 1.f : 0.f);
        const float w11 = dy * dx                 * ((vy1 && vx1) ? 1.f : 0.f);
        SC[u] = (unsigned)(y0c | (x0c << 7) | (y1c << 14) | (x1c << 21));
        SW[u] = make_uint2(pack_f16(w00, w01), pack_f16(w10, w11));
    }
    __syncthreads();           // setup visible

    f32x4 acc[4];
    #pragma unroll
    for (int mt = 0; mt < 4; mt++) acc[mt] = (f32x4){0.f, 0.f, 0.f, 0.f};

    uint4 rset[8];             // gathers for current tap: [round][corner]
    uint4 bset[2][2];          // double-buffered B frags (2 ksteps/stage)

    auto issue_stage = [&](int s) {
        #pragma unroll
        for (int r = 0; r < 2; r++) {
            const int p = pg + 32 * r;
            const unsigned int cc = SC[s * 64 + p];
            const int y0b = (int)(cc & 127) << 14;
            const int x0b = (int)((cc >> 7) & 127) << 7;
            const int y1b = (int)((cc >> 14) & 127) << 14;
            const int x1b = (int)(cc >> 21) << 7;
            const char* base = xb + q8 * 16;
            rset[4 * r + 0] = *(const uint4*)(base + (y0b | x0b));
            rset[4 * r + 1] = *(const uint4*)(base + (y0b | x1b));
            rset[4 * r + 2] = *(const uint4*)(base + (y1b | x0b));
            rset[4 * r + 3] = *(const uint4*)(base + (y1b | x1b));
        }
        bset[s & 1][0] = bq[((size_t)wid * KSTEPS + 2 * s) * 64 + lane];
        bset[s & 1][1] = bq[((size_t)wid * KSTEPS + 2 * s + 1) * 64 + lane];
    };
    auto blend_stage = [&](int s) {
        _Float16* dst = Abuf[s & 1];
        #pragma unroll
        for (int r = 0; r < 2; r++) {
            const int p = pg + 32 * r;
            const uint2 ww = SW[s * 64 + p];
            const f16x2 wA = __builtin_bit_cast(f16x2, ww.x);   // w00, w01
            const f16x2 wB = __builtin_bit_cast(f16x2, ww.y);   // w10, w11
            f16x8 sa = as_f16x8(rset[4 * r + 0]) * wA[0];
            sa += as_f16x8(rset[4 * r + 1]) * wA[1];
            sa += as_f16x8(rset[4 * r + 2]) * wB[0];
            sa += as_f16x8(rset[4 * r + 3]) * wB[1];
            *(f16x8*)&dst[p * 64 + ((q8 ^ (p & 7)) * 8)] = sa;
        }
    };
    auto mma_stage = [&](int s) {
        const _Float16* sub = Abuf[s & 1];
        #pragma unroll
        for (int ks = 0; ks < 2; ks++) {
            const f16x8 bf = __builtin_bit_cast(f16x8, bset[s & 1][ks]);
            const int slot = (ks * 4 + quad) ^ (n16 & 7);
            #pragma unroll
            for (int mt = 0; mt < 4; mt++) {
                const int rr = mt * 16 + n16;
                const f16x8 a = *(const f16x8*)&sub[rr * 64 + slot * 8];
                acc[mt] = __builtin_amdgcn_mfma_f32_16x16x32_f16(a, bf, acc[mt], 0, 0, 0);
            }
        }
    };

    issue_stage(0);
    #pragma unroll
    for (int s = 0; s < 9; s++) {
        blend_stage(s);                  // consumes rset (waits only its own loads)
        if (s < 8) issue_stage(s + 1);   // prefetch flies across barrier + MFMAs
        __syncthreads();
        mma_stage(s);
    }

    // Epilogue: D col = n16 (out channel within slab), row = quad*4+reg (pixel)
    const int o = wid * 16 + n16;
    #pragma unroll
    for (int mt = 0; mt < 4; mt++) {
        float4 v = make_float4(acc[mt].x, acc[mt].y, acc[mt].z, acc[mt].w);
        float* dst = out + ((size_t)(n * CCH + o)) * HW + px0 + mt * 16 + quad * 4;
        *(float4*)dst = v;
    }
}

extern "C" void kernel_launch(void* const* d_in, const int* in_sizes, int n_in,
                              void* d_out, int out_size, void* d_ws, size_t ws_size,
                              hipStream_t stream) {
    const float* x      = (const float*)d_in[0];   // [8,64,128,128]
    const float* offset = (const float*)d_in[1];   // [8,18,128,128]
    const float* weight = (const float*)d_in[2];   // [64,64,3,3]
    float* out = (float*)d_out;                    // [8,64,128,128]

    unsigned char* ws = (unsigned char*)d_ws;
    uint4*        bq   = (uint4*)ws;                        // 73728 B
    unsigned int* xt32 = (unsigned int*)(ws + 131072);      // 8 MB (f16 NHWC)
    const unsigned short* xt = (const unsigned short*)xt32;

    prep_kernel<<<2048 + 18, 256, 0, stream>>>(x, weight, xt32, bq);
    deform_mfma<<<2048, 256, 0, stream>>>(xt, offset, bq, out);
}